// Round 2
// baseline (282.372 us; speedup 1.0000x reference)
//
#include <hip/hip_runtime.h>
#include <cfloat>
#include <math.h>

#define BINS 64
#define NELEM (192*224*192)       // 8,257,536 per batch sample (C=1)
#define N4    (NELEM/4)           // 2,064,384 float4 per slice
#define NB 2
#define HIST_OFF 16               // ws u32 index where histograms start
#define T4 8                      // float4 loaded per thread per kernel pass
#define BLK 256
#define PER_BLOCK (T4*BLK)        // 2048 float4 per block
#define NBLK_SLICE (N4/PER_BLOCK) // 1008 blocks per slice (exact)

// ---- monotonic float<->uint key (unsigned ascending == float ascending) ----
__device__ __forceinline__ unsigned fkey(float f){
    unsigned u = __float_as_uint(f);
    return (u & 0x80000000u) ? ~u : (u | 0x80000000u);
}
__device__ __forceinline__ float funkey(unsigned k){
    unsigned u = (k & 0x80000000u) ? (k ^ 0x80000000u) : ~k;
    return __uint_as_float(u);
}

// ws layout (u32): [0..15] minmax keys: b*4 + {fmin,fmax,wmin,wmax}
//                  [16..16+NB*4096) joint histograms
__global__ void k_init(unsigned* ws){
    int i = blockIdx.x * 256 + threadIdx.x;
    if (i < 16) ws[i] = ((i & 1) == 0) ? 0xFFFFFFFFu : 0u;
    if (i < NB * BINS * BINS) ws[HIST_OFF + i] = 0u;
}

// grid (NBLK_SLICE, 4): y = 0:F/b0 1:F/b1 2:W/b0 3:W/b1
__global__ __launch_bounds__(BLK) void k_minmax(const float* __restrict__ F,
                                                const float* __restrict__ W,
                                                unsigned* ws){
    const int y = blockIdx.y;
    const int b = y & 1;
    const float4* S4 = (const float4*)((y < 2 ? F : W) + (size_t)b * NELEM);
    const int base = blockIdx.x * PER_BLOCK + threadIdx.x;

    float4 v[T4];
    #pragma unroll
    for (int k = 0; k < T4; ++k) v[k] = S4[base + k * BLK];   // 8 loads in flight

    // pairwise tree (independent ops -> ILP)
    float4 mn4 = v[0], mx4 = v[0];
    #pragma unroll
    for (int k = 1; k < T4; ++k){
        mn4.x = fminf(mn4.x, v[k].x); mn4.y = fminf(mn4.y, v[k].y);
        mn4.z = fminf(mn4.z, v[k].z); mn4.w = fminf(mn4.w, v[k].w);
        mx4.x = fmaxf(mx4.x, v[k].x); mx4.y = fmaxf(mx4.y, v[k].y);
        mx4.z = fmaxf(mx4.z, v[k].z); mx4.w = fmaxf(mx4.w, v[k].w);
    }
    float mn = fminf(fminf(mn4.x, mn4.y), fminf(mn4.z, mn4.w));
    float mx = fmaxf(fmaxf(mx4.x, mx4.y), fmaxf(mx4.z, mx4.w));

    for (int off = 32; off; off >>= 1){
        mn = fminf(mn, __shfl_down(mn, off));
        mx = fmaxf(mx, __shfl_down(mx, off));
    }
    __shared__ float s[4][2];
    int wave = threadIdx.x >> 6;
    if ((threadIdx.x & 63) == 0){ s[wave][0] = mn; s[wave][1] = mx; }
    __syncthreads();
    if (threadIdx.x == 0){
        float a0 = s[0][0], a1 = s[0][1];
        for (int wv = 1; wv < 4; ++wv){
            a0 = fminf(a0, s[wv][0]); a1 = fmaxf(a1, s[wv][1]);
        }
        const int slot = b * 4 + (y < 2 ? 0 : 2);
        atomicMin(&ws[slot],     fkey(a0));
        atomicMax(&ws[slot + 1], fkey(a1));
    }
}

// grid (NBLK_SLICE, NB): y = batch
__global__ __launch_bounds__(BLK) void k_hist(const float* __restrict__ F,
                                              const float* __restrict__ W,
                                              unsigned* ws){
    const int b = blockIdx.y;
    __shared__ unsigned h[BINS * BINS];

    const float fmn = funkey(ws[b*4+0]);
    const float fmx = funkey(ws[b*4+1]);
    const float wmn = funkey(ws[b*4+2]);
    const float wmx = funkey(ws[b*4+3]);
    const float fden = fmx - fmn + 1e-10f;   // exact ref f32 arithmetic
    const float wden = wmx - wmn + 1e-10f;

    const float4* F4 = (const float4*)(F + (size_t)b * NELEM);
    const float4* W4 = (const float4*)(W + (size_t)b * NELEM);
    const int base = blockIdx.x * PER_BLOCK + threadIdx.x;

    float4 fv[T4], wv[T4];
    #pragma unroll
    for (int k = 0; k < T4; ++k) fv[k] = F4[base + k * BLK];  // 16 loads in flight
    #pragma unroll
    for (int k = 0; k < T4; ++k) wv[k] = W4[base + k * BLK];

    for (int i = threadIdx.x; i < BINS * BINS; i += BLK) h[i] = 0u;
    __syncthreads();

    #pragma unroll
    for (int k = 0; k < T4; ++k){
        float fa[4] = {fv[k].x, fv[k].y, fv[k].z, fv[k].w};
        float wa[4] = {wv[k].x, wv[k].y, wv[k].z, wv[k].w};
        #pragma unroll
        for (int j = 0; j < 4; ++j){
            // exact ref order: ((x - xmin) / (xmax - xmin + EPS)) * 63, trunc, clamp
            int fi = (int)((fa[j] - fmn) / fden * 63.0f);
            int wi = (int)((wa[j] - wmn) / wden * 63.0f);
            fi = min(max(fi, 0), 63);
            wi = min(max(wi, 0), 63);
            atomicAdd(&h[fi * BINS + wi], 1u);
        }
    }
    __syncthreads();
    unsigned* gh = ws + HIST_OFF + b * BINS * BINS;
    for (int i = threadIdx.x; i < BINS * BINS; i += BLK){
        unsigned v = h[i];
        if (v) atomicAdd(&gh[i], v);
    }
}

__device__ double block_sum256(double v, double* sred){
    int t = threadIdx.x;
    sred[t] = v; __syncthreads();
    for (int off = 128; off; off >>= 1){
        if (t < off) sred[t] += sred[t + off];
        __syncthreads();
    }
    double r = sred[0]; __syncthreads();
    return r;
}

__global__ void k_final(const float* __restrict__ pa, const float* __restrict__ ta,
                        const unsigned* __restrict__ ws, float* __restrict__ out){
    __shared__ double sred[256];
    const unsigned* hist = ws + HIST_OFF;
    const float fN = (float)NELEM;   // exact in f32 (< 2^24)
    double loss_sim = 0.0;
    for (int b = 0; b < NB; ++b){
        const unsigned* H = hist + b * BINS * BINS;
        double hj_p = 0.0;
        for (int i = threadIdx.x; i < BINS * BINS; i += 256){
            float p = (float)H[i] / fN;
            hj_p += (double)(p * logf(p + 1e-10f));
        }
        double hj = -block_sum256(hj_p, sred);
        double hf_p = 0.0, hw_p = 0.0;
        if (threadIdx.x < BINS){
            int r = threadIdx.x;
            unsigned cf = 0, cw = 0;
            for (int j = 0; j < BINS; ++j){
                cf += H[r * BINS + j];
                cw += H[j * BINS + r];
            }
            float pf = (float)cf / fN, pw = (float)cw / fN;
            hf_p = (double)(pf * logf(pf + 1e-10f));
            hw_p = (double)(pw * logf(pw + 1e-10f));
        }
        double hf = -block_sum256(hf_p, sred);
        double hw = -block_sum256(hw_p, sred);
        double mi  = hf + hw - hj;
        double nmi = 2.0 * mi / (hf + hw + 1e-10);
        loss_sim += -nmi;
    }
    loss_sim /= (double)NB;
    if (threadIdx.x == 0){
        double a = 0.0;
        for (int i = 0; i < 24; ++i){
            double d = (double)pa[i] - (double)ta[i];
            a += d * d;
        }
        a /= 24.0;
        out[0] = (float)(a + loss_sim);
    }
}

extern "C" void kernel_launch(void* const* d_in, const int* in_sizes, int n_in,
                              void* d_out, int out_size, void* d_ws, size_t ws_size,
                              hipStream_t stream) {
    const float* pa = (const float*)d_in[0];
    const float* ta = (const float*)d_in[1];
    const float* F  = (const float*)d_in[2];
    const float* W  = (const float*)d_in[3];
    float* out = (float*)d_out;
    unsigned* ws = (unsigned*)d_ws;

    k_init<<<33, 256, 0, stream>>>(ws);
    k_minmax<<<dim3(NBLK_SLICE, 4), BLK, 0, stream>>>(F, W, ws);
    k_hist<<<dim3(NBLK_SLICE, NB), BLK, 0, stream>>>(F, W, ws);
    k_final<<<1, 256, 0, stream>>>(pa, ta, ws, out);
}